// Round 1
// baseline (829.541 us; speedup 1.0000x reference)
//
#include <hip/hip_runtime.h>
#include <hip/hip_bf16.h>
#include <math.h>

#define B_ 1024
#define H_ 4
#define D_ 128
#define V_ 100000
#define M_ (B_*H_)   // 4096
#define EPS_ 1e-7f

typedef unsigned short ushort_t;
typedef __attribute__((ext_vector_type(4))) float f32x4;
typedef __attribute__((ext_vector_type(8))) short bf16x8;

__device__ __forceinline__ ushort_t f2bf(float f) {
    unsigned u = __float_as_uint(f);
    unsigned r = u + 0x7fffu + ((u >> 16) & 1u);   // RNE
    return (ushort_t)(r >> 16);
}

__device__ __forceinline__ void gload_lds16(const void* g, void* l) {
    __builtin_amdgcn_global_load_lds(
        (const __attribute__((address_space(1))) unsigned int*)g,
        (__attribute__((address_space(3))) unsigned int*)l,
        16, 0, 0);
}

// ---------------------------------------------------------------------------
// Kernel A: proj = tanh(inputs @ proj_mat.T) -> bf16 [4096,128]; pi = softmax(inputs @ mix_mat.T)
// ---------------------------------------------------------------------------
__global__ __launch_bounds__(512)
void proj_pi_kernel(const float* __restrict__ inputs, const float* __restrict__ proj_mat,
                    const float* __restrict__ mix_mat, ushort_t* __restrict__ Abf,
                    float* __restrict__ pi)
{
    __shared__ float xin[128];
    __shared__ float mixv[4];
    const int b = blockIdx.x, tid = threadIdx.x;
    if (tid < 128) xin[tid] = inputs[b * 128 + tid];
    __syncthreads();

    // each thread computes proj column `tid` (0..511)
    const float4* row = (const float4*)(proj_mat + tid * 128);
    float acc = 0.f;
#pragma unroll 8
    for (int k = 0; k < 32; ++k) {
        float4 m4 = row[k];
        acc += m4.x * xin[k*4+0] + m4.y * xin[k*4+1] + m4.z * xin[k*4+2] + m4.w * xin[k*4+3];
    }
    Abf[b * 512 + tid] = f2bf(tanhf(acc));

    if (tid < 4) {
        const float4* mrow = (const float4*)(mix_mat + tid * 128);
        float a2 = 0.f;
#pragma unroll 8
        for (int k = 0; k < 32; ++k) {
            float4 m4 = mrow[k];
            a2 += m4.x * xin[k*4+0] + m4.y * xin[k*4+1] + m4.z * xin[k*4+2] + m4.w * xin[k*4+3];
        }
        mixv[tid] = a2;
    }
    __syncthreads();
    if (tid < 4) {
        float m = fmaxf(fmaxf(mixv[0], mixv[1]), fmaxf(mixv[2], mixv[3]));
        float e0 = __expf(mixv[0]-m), e1 = __expf(mixv[1]-m), e2 = __expf(mixv[2]-m), e3 = __expf(mixv[3]-m);
        float s = e0 + e1 + e2 + e3;
        float mye = __expf(mixv[tid]-m);
        pi[b * 4 + tid] = mye / s;
    }
}

// ---------------------------------------------------------------------------
// Kernel B: embeddings fp32 -> bf16
// ---------------------------------------------------------------------------
__global__ __launch_bounds__(256)
void conv_kernel(const float* __restrict__ e, ushort_t* __restrict__ o, int n4)
{
    int i = blockIdx.x * 256 + threadIdx.x;
    if (i < n4) {
        float4 f = ((const float4*)e)[i];
        ushort4 u;
        u.x = f2bf(f.x); u.y = f2bf(f.y); u.z = f2bf(f.z); u.w = f2bf(f.w);
        ((ushort4*)o)[i] = u;
    }
}

// ---------------------------------------------------------------------------
// GEMM passes. A=[4096,128] bf16 (m=b*4+h), E=[100000,128] bf16 (row=v).
// PASS 1: Z[m] += sum_v exp(logit)   (atomic)
// PASS 2: probs[b,v] = sum_h (pi/Z)[b,h] * exp(logit)
// Tile: 128(m) x 128(n), K=128 in one LDS stage, 4 waves each 64x64.
// ---------------------------------------------------------------------------
template <int PASS>
__global__ __launch_bounds__(256, 2)
void gemm_kernel(const ushort_t* __restrict__ Abf, const ushort_t* __restrict__ Ebf,
                 const float* __restrict__ pi, float* __restrict__ Z,
                 float* __restrict__ probs)
{
    __shared__ ushort_t lds_a[128 * 128];
    __shared__ ushort_t lds_b[128 * 128];
    __shared__ float w_lds[128];

    const int tid  = threadIdx.x;
    const int wave = tid >> 6;
    const int lane = tid & 63;
    const int q    = lane >> 4;
    const int r16  = lane & 15;
    const int m0   = blockIdx.x * 128;   // x = m-strip (32) fastest for emb L2 sharing
    const int v0   = blockIdx.y * 128;

    if (PASS == 2) {
        if (tid < 128) {
            int gi = m0 + tid;
            w_lds[tid] = pi[gi] / Z[gi];
        }
    }

    // --- staging: 8 iters x 4KB for each tile; LDS slot (r,c) <- global chunk c^(r&7) ---
#pragma unroll
    for (int t = 0; t < 8; ++t) {
        int r  = t * 16 + (tid >> 4);        // row 0..127
        int c  = tid & 15;                   // 16B chunk in row
        int cs = c ^ (r & 7);                // swizzled source chunk
        unsigned loff = (unsigned)__builtin_amdgcn_readfirstlane(t * 4096 + (tid >> 6) * 1024);
        // A tile
        gload_lds16(Abf + (size_t)(m0 + r) * 128 + cs * 8, (char*)lds_a + loff);
        // B tile (clamp v rows past V)
        int vrow = v0 + r; if (vrow >= V_) vrow = V_ - 1;
        gload_lds16(Ebf + (size_t)vrow * 128 + cs * 8, (char*)lds_b + loff);
    }
    __syncthreads();

    const int wm = (wave >> 1) * 64;
    const int wn = (wave & 1) * 64;

    f32x4 acc[4][4];
#pragma unroll
    for (int mi = 0; mi < 4; ++mi)
#pragma unroll
        for (int ni = 0; ni < 4; ++ni)
            acc[mi][ni] = (f32x4)(0.f);

#pragma unroll
    for (int kk = 0; kk < 4; ++kk) {
        bf16x8 fa[4], fb[4];
        int chunk = kk * 4 + q;
#pragma unroll
        for (int mi = 0; mi < 4; ++mi) {
            int row = wm + mi * 16 + r16;
            int sc = chunk ^ (row & 7);
            fa[mi] = *(const bf16x8*)&lds_a[row * 128 + sc * 8];
        }
#pragma unroll
        for (int ni = 0; ni < 4; ++ni) {
            int row = wn + ni * 16 + r16;
            int sc = chunk ^ (row & 7);
            fb[ni] = *(const bf16x8*)&lds_b[row * 128 + sc * 8];
        }
#pragma unroll
        for (int mi = 0; mi < 4; ++mi)
#pragma unroll
            for (int ni = 0; ni < 4; ++ni)
                acc[mi][ni] = __builtin_amdgcn_mfma_f32_16x16x32_bf16(fa[mi], fb[ni], acc[mi][ni], 0, 0, 0);
    }

    if (PASS == 1) {
        // per-lane partial sums over our 16 columns-block, indexed [mi][h]
        float zs[4][4];
#pragma unroll
        for (int mi = 0; mi < 4; ++mi)
#pragma unroll
            for (int h = 0; h < 4; ++h) zs[mi][h] = 0.f;

#pragma unroll
        for (int mi = 0; mi < 4; ++mi) {
#pragma unroll
            for (int ni = 0; ni < 4; ++ni) {
                int v = v0 + wn + ni * 16 + r16;
                bool ok = (v < V_);
#pragma unroll
                for (int h = 0; h < 4; ++h) {
                    float e = ok ? __expf(acc[mi][ni][h]) : 0.f;
                    zs[mi][h] += e;
                }
            }
        }
        // butterfly over lane bits 0..3 (the 16 columns)
#pragma unroll
        for (int msk = 1; msk < 16; msk <<= 1) {
#pragma unroll
            for (int mi = 0; mi < 4; ++mi)
#pragma unroll
                for (int h = 0; h < 4; ++h)
                    zs[mi][h] += __shfl_xor(zs[mi][h], msk, 64);
        }
        // lane r16 = mi*4+h writes its quad's (b,h)
        int mi = r16 >> 2, h = r16 & 3;
        int midx = m0 + wm + mi * 16 + q * 4 + h;
        atomicAdd(&Z[midx], zs[mi][h]);
    } else {
#pragma unroll
        for (int mi = 0; mi < 4; ++mi) {
            int mloc = wm + mi * 16 + q * 4;
            float w0 = w_lds[mloc + 0], w1 = w_lds[mloc + 1];
            float w2 = w_lds[mloc + 2], w3 = w_lds[mloc + 3];
            size_t rowoff = (size_t)((m0 + mloc) >> 2) * V_;
#pragma unroll
            for (int ni = 0; ni < 4; ++ni) {
                int v = v0 + wn + ni * 16 + r16;
                if (v < V_) {
                    f32x4 a = acc[mi][ni];
                    float p = w0 * __expf(a[0]) + w1 * __expf(a[1])
                            + w2 * __expf(a[2]) + w3 * __expf(a[3]);
                    probs[rowoff + v] = p;
                }
            }
        }
    }
}

// ---------------------------------------------------------------------------
// Loss: -mean(log(clip(probs[b,label[b]], 1e-7, 1)))
// ---------------------------------------------------------------------------
__global__ __launch_bounds__(256)
void loss_kernel(const float* __restrict__ probs, const int* __restrict__ label,
                 float* __restrict__ out)
{
    __shared__ float red[256];
    int tid = threadIdx.x;
    float s = 0.f;
    for (int b = tid; b < B_; b += 256) {
        float p = probs[(size_t)b * V_ + label[b]];
        p = fminf(fmaxf(p, EPS_), 1.0f);
        s -= logf(p);
    }
    red[tid] = s;
    __syncthreads();
    for (int st = 128; st > 0; st >>= 1) {
        if (tid < st) red[tid] += red[tid + st];
        __syncthreads();
    }
    if (tid == 0) out[0] = red[0] / (float)B_;
}

// ---------------------------------------------------------------------------
extern "C" void kernel_launch(void* const* d_in, const int* in_sizes, int n_in,
                              void* d_out, int out_size, void* d_ws, size_t ws_size,
                              hipStream_t stream)
{
    const float* inputs   = (const float*)d_in[0];
    const int*   label    = (const int*)d_in[1];
    const float* emb      = (const float*)d_in[2];
    const float* proj_mat = (const float*)d_in[3];
    const float* mix_mat  = (const float*)d_in[4];
    float* out = (float*)d_out;

    char* ws = (char*)d_ws;
    ushort_t* emb_bf = (ushort_t*)ws;                       // 25,600,000 B
    ushort_t* A_bf   = (ushort_t*)(ws + 25600000);          //  1,048,576 B
    float*    pi     = (float*)(ws + 26648576);             //     16,384 B
    float*    Z      = (float*)(ws + 26664960);             //     16,384 B

    conv_kernel<<<12500, 256, 0, stream>>>(emb, emb_bf, 3200000);
    proj_pi_kernel<<<1024, 512, 0, stream>>>(inputs, proj_mat, mix_mat, A_bf, pi);
    hipMemsetAsync(Z, 0, 4096 * sizeof(float), stream);

    dim3 g(32, 782);
    gemm_kernel<1><<<g, 256, 0, stream>>>(A_bf, emb_bf, nullptr, Z, nullptr);
    gemm_kernel<2><<<g, 256, 0, stream>>>(A_bf, emb_bf, pi, Z, out);

    loss_kernel<<<1, 256, 0, stream>>>(out, label, out + (size_t)B_ * V_);
}